// Round 1
// baseline (1989.435 us; speedup 1.0000x reference)
//
#include <hip/hip_runtime.h>

#define NI 8
#define NH 64
#define NO 8
#define NB 256
#define NT 2048

// tanh(s) = 1 - 2/(exp(2s)+1); safe at +-inf (exp overflow -> 1, underflow -> -1)
__device__ __forceinline__ float tanh_fast(float s) {
    float e = __expf(2.0f * s);
    return fmaf(-2.0f, __builtin_amdgcn_rcpf(e + 1.0f), 1.0f);
}

__global__ void __launch_bounds__(64, 1) rnn_fused(
    const float* __restrict__ x,
    const float* __restrict__ W_ih0, const float* __restrict__ W_hh0,
    const float* __restrict__ b_ih0, const float* __restrict__ b_hh0,
    const float* __restrict__ W_ih1, const float* __restrict__ W_hh1,
    const float* __restrict__ b_ih1, const float* __restrict__ b_hh1,
    const float* __restrict__ W_fc,  const float* __restrict__ b_fc,
    float* __restrict__ out)
{
    const int b    = blockIdx.x;   // batch element
    const int lane = threadIdx.x;  // output neuron j (0..63)

    // ---- weights into registers (lane j holds row j of each matrix) ----
    float wih0[NI];
    #pragma unroll
    for (int i = 0; i < NI; ++i) wih0[i] = W_ih0[lane * NI + i];
    float whh0[NH], wih1[NH], whh1[NH];
    #pragma unroll
    for (int k = 0; k < NH; ++k) whh0[k] = W_hh0[lane * NH + k];
    #pragma unroll
    for (int k = 0; k < NH; ++k) wih1[k] = W_ih1[lane * NH + k];
    #pragma unroll
    for (int k = 0; k < NH; ++k) whh1[k] = W_hh1[lane * NH + k];
    const float bias0 = b_ih0[lane] + b_hh0[lane];
    const float bias1 = b_ih1[lane] + b_hh1[lane];

    // ---- FC slice: lane = (kg, o); out[o] partial over k in [kg*8, kg*8+8) ----
    const int o  = lane & 7;
    const int kg = lane >> 3;
    float wfc[8];
    #pragma unroll
    for (int m = 0; m < 8; ++m) wfc[m] = W_fc[o * NH + kg * 8 + m];
    const float bfc = b_fc[o];

    __shared__ float xs[64 * NI];  // 64 timesteps of x
    __shared__ float hb0[NH];      // h0[t] publish buffer
    __shared__ float hb1[NH];      // h1[t-1] publish buffer

    float h0r[NH];                 // h0[t-1] replicated in registers
    #pragma unroll
    for (int k = 0; k < NH; ++k) h0r[k] = 0.0f;
    float h1_prev = 0.0f;          // h1[t-1][lane] scalar
    float h0_last = 0.0f, h1_last = 0.0f;

    const float* xb   = x   + (size_t)b * NT * NI;
    float*       outb = out + (size_t)b * NT * NO;

    for (int tc = 0; tc < NT; tc += 64) {
        // stage next 64 timesteps of x (coalesced: lane l loads timestep tc+l)
        float4 xa = *(const float4*)(xb + (size_t)(tc + lane) * NI);
        float4 xc = *(const float4*)(xb + (size_t)(tc + lane) * NI + 4);
        __syncthreads();
        *(float4*)(xs + lane * NI)     = xa;
        *(float4*)(xs + lane * NI + 4) = xc;
        __syncthreads();

        #pragma unroll 1
        for (int tt = 0; tt < 64; ++tt) {
            const int t = tc + tt;

            // ---- layer 0: s0 = x[t]@wih0_row + h0[t-1]@whh0_row + bias0 ----
            float4 x0 = *(const float4*)(xs + tt * NI);
            float4 x1 = *(const float4*)(xs + tt * NI + 4);
            float a0 = bias0, a1 = 0.f, a2 = 0.f, a3 = 0.f;
            a0 = fmaf(x0.x, wih0[0], a0); a1 = fmaf(x0.y, wih0[1], a1);
            a2 = fmaf(x0.z, wih0[2], a2); a3 = fmaf(x0.w, wih0[3], a3);
            a0 = fmaf(x1.x, wih0[4], a0); a1 = fmaf(x1.y, wih0[5], a1);
            a2 = fmaf(x1.z, wih0[6], a2); a3 = fmaf(x1.w, wih0[7], a3);
            #pragma unroll
            for (int k = 0; k < NH; k += 4) {
                a0 = fmaf(h0r[k+0], whh0[k+0], a0);
                a1 = fmaf(h0r[k+1], whh0[k+1], a1);
                a2 = fmaf(h0r[k+2], whh0[k+2], a2);
                a3 = fmaf(h0r[k+3], whh0[k+3], a3);
            }
            float h0n = tanh_fast((a0 + a1) + (a2 + a3));

            // ---- publish h0[t] and h1[t-1]; single sync per step ----
            hb0[lane] = h0n;
            hb1[lane] = h1_prev;
            __syncthreads();

            // ---- layer 1: gather h0[t] (keep for next step) and h1[t-1], fused dots ----
            float c0 = bias1, c1 = 0.f, c2 = 0.f, c3 = 0.f;
            #pragma unroll
            for (int k = 0; k < NH; k += 4) {
                float4 v = *(const float4*)(hb0 + k);   // broadcast read
                c0 = fmaf(v.x, wih1[k+0], c0);
                c1 = fmaf(v.y, wih1[k+1], c1);
                c2 = fmaf(v.z, wih1[k+2], c2);
                c3 = fmaf(v.w, wih1[k+3], c3);
                h0r[k+0] = v.x; h0r[k+1] = v.y; h0r[k+2] = v.z; h0r[k+3] = v.w;
            }
            #pragma unroll
            for (int k = 0; k < NH; k += 4) {
                float4 v = *(const float4*)(hb1 + k);   // broadcast read
                c0 = fmaf(v.x, whh1[k+0], c0);
                c1 = fmaf(v.y, whh1[k+1], c1);
                c2 = fmaf(v.z, whh1[k+2], c2);
                c3 = fmaf(v.w, whh1[k+3], c3);
            }
            float h1n = tanh_fast((c0 + c1) + (c2 + c3));

            // ---- FC for step t-1 (h1[t-1] is in hb1) ----
            float4 u0 = *(const float4*)(hb1 + kg * 8);
            float4 u1 = *(const float4*)(hb1 + kg * 8 + 4);
            float p = u0.x*wfc[0] + u0.y*wfc[1] + u0.z*wfc[2] + u0.w*wfc[3]
                    + u1.x*wfc[4] + u1.y*wfc[5] + u1.z*wfc[6] + u1.w*wfc[7];
            p += __shfl_xor(p, 8);
            p += __shfl_xor(p, 16);
            p += __shfl_xor(p, 32);
            if (t > 0 && lane < 8) outb[(size_t)(t - 1) * NO + o] = p + bfc;

            h1_prev = h1n;
            h0_last = h0n;
            h1_last = h1n;
        }
    }

    // ---- epilogue: FC for t = NT-1 ----
    __syncthreads();
    hb1[lane] = h1_prev;
    __syncthreads();
    {
        float4 u0 = *(const float4*)(hb1 + kg * 8);
        float4 u1 = *(const float4*)(hb1 + kg * 8 + 4);
        float p = u0.x*wfc[0] + u0.y*wfc[1] + u0.z*wfc[2] + u0.w*wfc[3]
                + u1.x*wfc[4] + u1.y*wfc[5] + u1.z*wfc[6] + u1.w*wfc[7];
        p += __shfl_xor(p, 8);
        p += __shfl_xor(p, 16);
        p += __shfl_xor(p, 32);
        if (lane < 8) outb[(size_t)(NT - 1) * NO + o] = p + bfc;
    }

    // ---- hidden state: [2, B, H] appended after out ----
    const size_t hid_base = (size_t)NB * NT * NO;
    out[hid_base + (size_t)b * NH + lane]                    = h0_last;
    out[hid_base + (size_t)NB * NH + (size_t)b * NH + lane]  = h1_last;
}

extern "C" void kernel_launch(void* const* d_in, const int* in_sizes, int n_in,
                              void* d_out, int out_size, void* d_ws, size_t ws_size,
                              hipStream_t stream) {
    const float* x     = (const float*)d_in[0];
    const float* W_ih0 = (const float*)d_in[1];
    const float* W_hh0 = (const float*)d_in[2];
    const float* b_ih0 = (const float*)d_in[3];
    const float* b_hh0 = (const float*)d_in[4];
    const float* W_ih1 = (const float*)d_in[5];
    const float* W_hh1 = (const float*)d_in[6];
    const float* b_ih1 = (const float*)d_in[7];
    const float* b_hh1 = (const float*)d_in[8];
    const float* W_fc  = (const float*)d_in[9];
    const float* b_fc  = (const float*)d_in[10];

    rnn_fused<<<dim3(NB), dim3(64), 0, stream>>>(
        x, W_ih0, W_hh0, b_ih0, b_hh0,
        W_ih1, W_hh1, b_ih1, b_hh1, W_fc, b_fc,
        (float*)d_out);
}

// Round 2
// 1372.367 us; speedup vs baseline: 1.4496x; 1.4496x over previous
//
#include <hip/hip_runtime.h>

#define NI 8
#define NH 64
#define NO 8
#define NB 256
#define NT 2048
#define NCHUNK (NT / 64)   // 32 chunks of 64 timesteps

// tanh(s) = 1 - 2/(exp(2s)+1); safe at +-inf
__device__ __forceinline__ float tanh_fast(float s) {
    float e = __expf(2.0f * s);
    return fmaf(-2.0f, __builtin_amdgcn_rcpf(e + 1.0f), 1.0f);
}

// 4-wave pipeline, one block per batch element.
//   wave0: h0[n]      = tanh(x[n]@Wih0^T + b0 + h0[n-1]@Whh0^T)        (n in [0,NT-1])
//   wave1: pih[n-1]   = h0[n-1]@Wih1^T + b1                             (n in [1,NT])
//   wave2: h1[n-2]    = tanh(pih[n-2] + h1[n-3]@Whh1^T)                 (n in [2,NT+1])
//   wave3: out[n-3]   = h1[n-3]@Wfc^T + bfc ; x-chunk staging           (n in [3,NT+2])
// All reads from buf[p], all writes to buf[p^1], p = n&1; ONE barrier per step.
__global__ void __launch_bounds__(256, 1) rnn_pipe(
    const float* __restrict__ x,
    const float* __restrict__ W_ih0, const float* __restrict__ W_hh0,
    const float* __restrict__ b_ih0, const float* __restrict__ b_hh0,
    const float* __restrict__ W_ih1, const float* __restrict__ W_hh1,
    const float* __restrict__ b_ih1, const float* __restrict__ b_hh1,
    const float* __restrict__ W_fc,  const float* __restrict__ b_fc,
    float* __restrict__ out)
{
    const int b    = blockIdx.x;
    const int tid  = threadIdx.x;
    const int wid  = tid >> 6;
    const int lane = tid & 63;

    __shared__ float xs[2][64][NI];      // double-buffered x chunks
    __shared__ float h0buf[2][NH];
    __shared__ float h1buf[2][NH];
    __shared__ float pibuf[2][NH];

    // zero-init state buffers (both parities)
    if (tid < 2 * NH) {
        ((float*)h0buf)[tid] = 0.0f;
        ((float*)h1buf)[tid] = 0.0f;
        ((float*)pibuf)[tid] = 0.0f;
    }

    // ---- per-wave weights (each wave's live set <= ~80 regs -> no spill) ----
    float wrow[NH];   // whh0 / wih1 / whh1 depending on wave
    float wsm[8];     // wih0 (wave0) or wfc (wave3)
    float bias = 0.0f;

    if (wid == 0) {
        #pragma unroll
        for (int k = 0; k < NH; ++k) wrow[k] = W_hh0[lane * NH + k];
        #pragma unroll
        for (int i = 0; i < NI; ++i) wsm[i] = W_ih0[lane * NI + i];
        bias = b_ih0[lane] + b_hh0[lane];
    } else if (wid == 1) {
        #pragma unroll
        for (int k = 0; k < NH; ++k) wrow[k] = W_ih1[lane * NH + k];
        bias = b_ih1[lane] + b_hh1[lane];
    } else if (wid == 2) {
        #pragma unroll
        for (int k = 0; k < NH; ++k) wrow[k] = W_hh1[lane * NH + k];
    } else {
        const int o  = lane & 7;
        const int kg = lane >> 3;
        #pragma unroll
        for (int m = 0; m < 8; ++m) wsm[m] = W_fc[o * NH + kg * 8 + m];
        bias = b_fc[o];
    }

    const float* xb   = x   + (size_t)b * NT * NI;
    float*       outb = out + (size_t)b * NT * NO;

    // ---- prologue: wave3 stages chunk 0 ----
    if (wid == 3) {
        float4 a0 = *(const float4*)(xb + (size_t)lane * NI);
        float4 a1 = *(const float4*)(xb + (size_t)lane * NI + 4);
        *(float4*)(&xs[0][lane][0]) = a0;
        *(float4*)(&xs[0][lane][4]) = a1;
    }
    __syncthreads();

    float h_keep = 0.0f;             // wave0: h0[NT-1]; wave2: h1[NT-1]
    float4 pend0 = {0, 0, 0, 0}, pend1 = {0, 0, 0, 0};   // wave3 staging regs
    int p = 0;

    for (int n = 0; n < NT + 3; ++n) {
        if (wid == 0) {
            if (n < NT) {
                float a0 = bias, a1 = 0.f, a2 = 0.f, a3 = 0.f;
                #pragma unroll
                for (int k = 0; k < NH; k += 4) {
                    float4 v = *(const float4*)(&h0buf[p][k]);   // broadcast
                    a0 = fmaf(v.x, wrow[k + 0], a0);
                    a1 = fmaf(v.y, wrow[k + 1], a1);
                    a2 = fmaf(v.z, wrow[k + 2], a2);
                    a3 = fmaf(v.w, wrow[k + 3], a3);
                }
                const int tt = n & 63, cb = (n >> 6) & 1;
                float4 x0 = *(const float4*)(&xs[cb][tt][0]);
                float4 x1 = *(const float4*)(&xs[cb][tt][4]);
                a0 = fmaf(x0.x, wsm[0], a0); a1 = fmaf(x0.y, wsm[1], a1);
                a2 = fmaf(x0.z, wsm[2], a2); a3 = fmaf(x0.w, wsm[3], a3);
                a0 = fmaf(x1.x, wsm[4], a0); a1 = fmaf(x1.y, wsm[5], a1);
                a2 = fmaf(x1.z, wsm[6], a2); a3 = fmaf(x1.w, wsm[7], a3);
                float h0n = tanh_fast((a0 + a1) + (a2 + a3));
                h0buf[p ^ 1][lane] = h0n;
                h_keep = h0n;
            }
        } else if (wid == 1) {
            if (n >= 1 && n <= NT) {
                float a0 = bias, a1 = 0.f, a2 = 0.f, a3 = 0.f;
                #pragma unroll
                for (int k = 0; k < NH; k += 4) {
                    float4 v = *(const float4*)(&h0buf[p][k]);   // broadcast
                    a0 = fmaf(v.x, wrow[k + 0], a0);
                    a1 = fmaf(v.y, wrow[k + 1], a1);
                    a2 = fmaf(v.z, wrow[k + 2], a2);
                    a3 = fmaf(v.w, wrow[k + 3], a3);
                }
                pibuf[p ^ 1][lane] = (a0 + a1) + (a2 + a3);
            }
        } else if (wid == 2) {
            if (n >= 2 && n <= NT + 1) {
                float a0 = pibuf[p][lane], a1 = 0.f, a2 = 0.f, a3 = 0.f;
                #pragma unroll
                for (int k = 0; k < NH; k += 4) {
                    float4 v = *(const float4*)(&h1buf[p][k]);   // broadcast
                    a0 = fmaf(v.x, wrow[k + 0], a0);
                    a1 = fmaf(v.y, wrow[k + 1], a1);
                    a2 = fmaf(v.z, wrow[k + 2], a2);
                    a3 = fmaf(v.w, wrow[k + 3], a3);
                }
                float h1n = tanh_fast((a0 + a1) + (a2 + a3));
                h1buf[p ^ 1][lane] = h1n;
                h_keep = h1n;
            }
        } else {
            // ---- FC for step n-3 ----
            if (n >= 3) {
                const int o  = lane & 7;
                const int kg = lane >> 3;
                float4 u0 = *(const float4*)(&h1buf[p][kg * 8]);
                float4 u1 = *(const float4*)(&h1buf[p][kg * 8 + 4]);
                float s = u0.x * wsm[0] + u0.y * wsm[1] + u0.z * wsm[2] + u0.w * wsm[3]
                        + u1.x * wsm[4] + u1.y * wsm[5] + u1.z * wsm[6] + u1.w * wsm[7];
                s += __shfl_xor(s, 8);
                s += __shfl_xor(s, 16);
                s += __shfl_xor(s, 32);
                if (lane < 8) outb[(size_t)(n - 3) * NO + o] = s + bias;
            }
            // ---- x staging: issue loads at m==0, LDS-write at m==16 ----
            const int m = n & 63;
            if (m == 0) {
                const int c = (n >> 6) + 1;
                if (c < NCHUNK) {
                    pend0 = *(const float4*)(xb + (size_t)(c * 64 + lane) * NI);
                    pend1 = *(const float4*)(xb + (size_t)(c * 64 + lane) * NI + 4);
                }
            } else if (m == 16) {
                const int c = (n >> 6) + 1;
                if (c < NCHUNK) {
                    *(float4*)(&xs[c & 1][lane][0]) = pend0;
                    *(float4*)(&xs[c & 1][lane][4]) = pend1;
                }
            }
        }
        __syncthreads();
        p ^= 1;
    }

    // ---- hidden state epilogue: [2, B, H] after out ----
    const size_t hid_base = (size_t)NB * NT * NO;
    if (wid == 0) out[hid_base + (size_t)b * NH + lane] = h_keep;                    // h0[NT-1]
    if (wid == 2) out[hid_base + (size_t)NB * NH + (size_t)b * NH + lane] = h_keep;  // h1[NT-1]
}

extern "C" void kernel_launch(void* const* d_in, const int* in_sizes, int n_in,
                              void* d_out, int out_size, void* d_ws, size_t ws_size,
                              hipStream_t stream) {
    const float* x     = (const float*)d_in[0];
    const float* W_ih0 = (const float*)d_in[1];
    const float* W_hh0 = (const float*)d_in[2];
    const float* b_ih0 = (const float*)d_in[3];
    const float* b_hh0 = (const float*)d_in[4];
    const float* W_ih1 = (const float*)d_in[5];
    const float* W_hh1 = (const float*)d_in[6];
    const float* b_ih1 = (const float*)d_in[7];
    const float* b_hh1 = (const float*)d_in[8];
    const float* W_fc  = (const float*)d_in[9];
    const float* b_fc  = (const float*)d_in[10];

    rnn_pipe<<<dim3(NB), dim3(256), 0, stream>>>(
        x, W_ih0, W_hh0, b_ih0, b_hh0,
        W_ih1, W_hh1, b_ih1, b_hh1, W_fc, b_fc,
        (float*)d_out);
}